// Round 4
// baseline (209.584 us; speedup 1.0000x reference)
//
#include <hip/hip_runtime.h>
#include <hip/hip_bf16.h>

typedef unsigned short u16;
typedef unsigned int   u32;
typedef u32 __attribute__((address_space(1))) gas_u32;
typedef u32 __attribute__((address_space(3))) las_u32;
typedef __bf16 bf16x8 __attribute__((ext_vector_type(8)));
typedef float  f32x4  __attribute__((ext_vector_type(4)));

constexpr int BATCH = 4, SEQ = 4096, HID = 1024, NH = 16, DH = 64;
constexpr int M  = BATCH * SEQ;   // 16384 rows
constexpr int KD = HID;           // 1024 (K of all GEMMs)

__device__ __forceinline__ u16 f2bf(float f) {
  __hip_bfloat16 h = __float2bfloat16(f);
  u16 u; __builtin_memcpy(&u, &h, 2); return u;
}
__device__ __forceinline__ float bf2f(u16 u) {
  u32 x = ((u32)u) << 16; float f; __builtin_memcpy(&f, &x, 4); return f;
}

// ---------------- prep kernels ----------------

// x (fp32) -> xb (bf16), 8 elems/thread, exact grid
__global__ __launch_bounds__(256) void cast_x_kernel(const float4* __restrict__ x,
                                                     uint4* __restrict__ xb) {
  int i = blockIdx.x * 256 + threadIdx.x;      // 2,097,152 threads
  float4 a = x[2 * i], b = x[2 * i + 1];
  uint4 o;
  o.x = (u32)f2bf(a.x) | ((u32)f2bf(a.y) << 16);
  o.y = (u32)f2bf(a.z) | ((u32)f2bf(a.w) << 16);
  o.z = (u32)f2bf(b.x) | ((u32)f2bf(b.y) << 16);
  o.w = (u32)f2bf(b.z) | ((u32)f2bf(b.w) << 16);
  xb[i] = o;
}

// Wk, Wo (K x N fp32) -> WkT, WoT (N x K bf16)
__global__ __launch_bounds__(256) void transpose_cast(const float* __restrict__ Wk,
                                                      const float* __restrict__ Wo,
                                                      u16* __restrict__ WkT,
                                                      u16* __restrict__ WoT) {
  __shared__ float tile[32][33];
  const float* src = blockIdx.z ? Wo : Wk;
  u16* dst = blockIdx.z ? WoT : WkT;
  int bx = blockIdx.x * 32, by = blockIdx.y * 32;
  int tx = threadIdx.x & 31, ty = threadIdx.x >> 5;   // 32 x 8
#pragma unroll
  for (int i = 0; i < 4; i++)
    tile[ty + i * 8][tx] = src[(size_t)(by + ty + i * 8) * HID + bx + tx];
  __syncthreads();
#pragma unroll
  for (int i = 0; i < 4; i++)
    dst[(size_t)(bx + ty + i * 8) * HID + by + tx] = f2bf(tile[tx][ty + i * 8]);
}

// WsT (128 x 1024 bf16, row-major N x K): rows 0..15 = colsum(Wq) per head,
// 16..31 = colsum(Wv), 32..47 = Wbeta, 48..127 = zero (padding for BN=128 tile)
__global__ __launch_bounds__(256) void build_wsum(const float* __restrict__ Wq,
                                                  const float* __restrict__ Wv,
                                                  const float* __restrict__ Wbeta,
                                                  u16* __restrict__ WsT) {
  int tid = blockIdx.x * 256 + threadIdx.x;   // 131072
  int c = tid >> 10, kk = tid & 1023;
  float s = 0.f;
  if (c < 16)      { for (int d = 0; d < DH; d++) s += Wq[(size_t)kk * HID + c * DH + d]; }
  else if (c < 32) { for (int d = 0; d < DH; d++) s += Wv[(size_t)kk * HID + (c - 16) * DH + d]; }
  else if (c < 48) { s = Wbeta[(size_t)kk * NH + (c - 32)]; }
  WsT[(size_t)c * HID + kk] = f2bf(s);
}

// ---------------- bf16 MFMA GEMM (m97 structure; NO XCD swizzle) ----------------
// R3 post-mortem: T1 swizzle costs 22-35% here (L3-resident problem, wrong
// regime — m160). Identity block mapping measured at 68 us (R1).
// C(MxN) = A(MxK) * Bt(NxK)^T ; BK=64, 256 threads = 4 waves.
// EPI 0: store bf16 C.
// EPI 2: y = bf16(xres + C + bias) to Cb (Cb != xres, both restrict).
// EPI 3: merged: blocks bn < nbn-1 behave like EPI 0 on Bt; block bn == nbn-1
//        uses Bt2 (WsT) and runs the skinny head-stat epilogue (sigmoid beta).
template <int BM, int BN, int WGM, int WGN, int EPI>
__global__ __launch_bounds__(256) void gemm_bf16(
    const u16* __restrict__ A, const u16* __restrict__ Bt,
    const u16* __restrict__ Bt2, int N, int K, int nbn,
    u16* __restrict__ Cb, const u16* __restrict__ xres,
    const float* __restrict__ bias, float* __restrict__ sq,
    float* __restrict__ sv, float* __restrict__ sb) {
  constexpr int BK = 64;
  constexpr int WTM = BM / WGM, WTN = BN / WGN, FM = WTM / 16, FN = WTN / 16;
  __shared__ u16 As[BM * BK];
  __shared__ u16 Bs[BN * BK];
  const int tid = threadIdx.x, wave = tid >> 6, lane = tid & 63;
  const int bm = (int)blockIdx.x / nbn, bn = (int)blockIdx.x % nbn;
  const int wm = wave / WGN, wn = wave % WGN;
  const int r16 = lane & 15, hi = lane >> 4;
  const int rsub = lane >> 3, csub = (lane & 7) * 8;

  bool skinny = false;
  const u16* Bbase = Bt;
  if constexpr (EPI == 3) {
    skinny = (bn == nbn - 1);
    if (skinny) Bbase = Bt2;
  }

  f32x4 acc[FM][FN] = {};

  const u16* Ab = A + (size_t)bm * BM * K;
  const u16* Bb = skinny ? Bbase : Bbase + (size_t)bn * BN * K;

  for (int kt = 0; kt < K; kt += BK) {
    {  // stage A and B tiles: linear LDS, wave-uniform base + lane*16B
      constexpr int PWA = BM / 32;
#pragma unroll
      for (int i = 0; i < PWA; i++) {
        int slot = wave * PWA + i;
        const u16* g = Ab + (size_t)(slot * 8 + rsub) * K + kt + csub;
        __builtin_amdgcn_global_load_lds((gas_u32*)g, (las_u32*)(As + slot * 512), 16, 0, 0);
      }
      constexpr int PWB = BN / 32;
#pragma unroll
      for (int i = 0; i < PWB; i++) {
        int slot = wave * PWB + i;
        const u16* g = Bb + (size_t)(slot * 8 + rsub) * K + kt + csub;
        __builtin_amdgcn_global_load_lds((gas_u32*)g, (las_u32*)(Bs + slot * 512), 16, 0, 0);
      }
    }
    __syncthreads();  // compiler drains vmcnt(0) before s_barrier
#pragma unroll
    for (int kk = 0; kk < BK / 32; kk++) {
      bf16x8 af[FM], bfr[FN];
#pragma unroll
      for (int f = 0; f < FM; f++)
        af[f] = *(const bf16x8*)(As + (wm * WTM + f * 16 + r16) * BK + kk * 32 + hi * 8);
#pragma unroll
      for (int f = 0; f < FN; f++)
        bfr[f] = *(const bf16x8*)(Bs + (wn * WTN + f * 16 + r16) * BK + kk * 32 + hi * 8);
#pragma unroll
      for (int fm = 0; fm < FM; fm++)
#pragma unroll
        for (int fn = 0; fn < FN; fn++)
          acc[fm][fn] = __builtin_amdgcn_mfma_f32_16x16x32_bf16(af[fm], bfr[fn], acc[fm][fn], 0, 0, 0);
    }
    __syncthreads();
  }

#pragma unroll
  for (int fm = 0; fm < FM; fm++) {
#pragma unroll
    for (int fn = 0; fn < FN; fn++) {
      const int lcol = wn * WTN + fn * 16 + r16;       // col within tile
      const int col = bn * BN + lcol;                  // global col (non-skinny)
#pragma unroll
      for (int j = 0; j < 4; j++) {
        const int row = bm * BM + wm * WTM + fm * 16 + hi * 4 + j;
        float v = acc[fm][fn][j];
        if constexpr (EPI == 2) {
          float y = bf2f(xres[(size_t)row * N + col]) + v + bias[col];
          Cb[(size_t)row * N + col] = f2bf(y);
        } else if constexpr (EPI == 3) {
          if (skinny) {
            const int b = row >> 12, t = row & 4095;
            if (lcol < 16)      sq[((size_t)(b * 16 + lcol)) * SEQ + t] = v;
            else if (lcol < 32) sv[((size_t)(b * 16 + lcol - 16)) * SEQ + t] = v;
            else if (lcol < 48) {
              float z = v + bias[lcol - 32];
              sb[((size_t)(b * 16 + lcol - 32)) * SEQ + t] = 1.f / (1.f + __expf(-z));
            }
          } else {
            Cb[(size_t)row * N + col] = f2bf(v);
          }
        } else {
          Cb[(size_t)row * N + col] = f2bf(v);
        }
      }
    }
  }
}

// ---------------- chunked scan: r_t = b_t*r_{t-1} + k_t*vsum_t ----------------
// 64 sequences (b,head) x 64 chunks of 64 steps. lane = d.

__global__ __launch_bounds__(256) void scan_chunks(const u16* __restrict__ kbuf,
                                                   const float* __restrict__ sv_t,
                                                   const float* __restrict__ sb_t,
                                                   float* __restrict__ Pbuf,
                                                   float* __restrict__ Rloc) {
  const int wave = threadIdx.x >> 6, lane = threadIdx.x & 63;
  const int gid = blockIdx.x * 4 + wave;       // [0, 4096)
  const int seq = gid >> 6, chunk = gid & 63;
  const int b = seq >> 4, h = seq & 15;
  const int t0 = chunk * 64;
  const float bet = sb_t[(size_t)seq * SEQ + t0 + lane];
  const float vs  = sv_t[(size_t)seq * SEQ + t0 + lane];
  const u16* kp = kbuf + ((size_t)(b * SEQ + t0)) * HID + h * DH + lane;
  float r = 0.f, P = 1.f;
#pragma unroll
  for (int tt = 0; tt < 64; tt += 8) {
    u16 kr[8];
#pragma unroll
    for (int j = 0; j < 8; j++) kr[j] = kp[(size_t)(tt + j) * HID];
#pragma unroll
    for (int j = 0; j < 8; j++) {
      float bt = __shfl(bet, tt + j);
      float vt = __shfl(vs, tt + j);
      r = fmaf(r, bt, bf2f(kr[j]) * vt);
      P *= bt;
    }
  }
  Rloc[(size_t)gid * 64 + lane] = r;
  if (lane == 0) Pbuf[gid] = P;
}

__global__ __launch_bounds__(64) void scan_prefix(const float* __restrict__ Pbuf,
                                                  const float* __restrict__ Rloc,
                                                  float* __restrict__ Rin) {
  const int seq = blockIdx.x, lane = threadIdx.x;
  const float* pp = Pbuf + seq * 64;
  const float* rl = Rloc + (size_t)seq * 64 * 64 + lane;
  float* ri = Rin + (size_t)seq * 64 * 64 + lane;
  float rin = 0.f;
#pragma unroll
  for (int c0 = 0; c0 < 64; c0 += 8) {
    float P[8], L[8];
#pragma unroll
    for (int j = 0; j < 8; j++) { P[j] = pp[c0 + j]; L[j] = rl[(size_t)(c0 + j) * 64]; }
#pragma unroll
    for (int j = 0; j < 8; j++) {
      ri[(size_t)(c0 + j) * 64] = rin;       // state ENTERING chunk c0+j
      rin = fmaf(P[j], rin, L[j]);
    }
  }
}

__global__ __launch_bounds__(256) void scan_apply(const u16* __restrict__ kbuf,
                                                  const float* __restrict__ sq_t,
                                                  const float* __restrict__ sv_t,
                                                  const float* __restrict__ sb_t,
                                                  const float* __restrict__ Rin,
                                                  u16* __restrict__ obuf) {
  const int wave = threadIdx.x >> 6, lane = threadIdx.x & 63;
  const int gid = blockIdx.x * 4 + wave;
  const int seq = gid >> 6, chunk = gid & 63;
  const int b = seq >> 4, h = seq & 15;
  const int t0 = chunk * 64;
  const float bet = sb_t[(size_t)seq * SEQ + t0 + lane];
  const float vs  = sv_t[(size_t)seq * SEQ + t0 + lane];
  const float qs  = sq_t[(size_t)seq * SEQ + t0 + lane];
  const u16* kp = kbuf + ((size_t)(b * SEQ + t0)) * HID + h * DH + lane;
  u16* op = obuf + ((size_t)(b * SEQ + t0)) * HID + h * DH + lane;
  float r = Rin[(size_t)gid * 64 + lane];
#pragma unroll
  for (int tt = 0; tt < 64; tt += 8) {
    u16 kr[8];
#pragma unroll
    for (int j = 0; j < 8; j++) kr[j] = kp[(size_t)(tt + j) * HID];
#pragma unroll
    for (int j = 0; j < 8; j++) {
      float bt = __shfl(bet, tt + j);
      float vt = __shfl(vs, tt + j);
      float qt = __shfl(qs, tt + j);
      r = fmaf(r, bt, bf2f(kr[j]) * vt);
      op[(size_t)(tt + j) * HID] = f2bf(qt * r);
    }
  }
}

// ---------------- LayerNorm (row per block) ----------------
__global__ __launch_bounds__(256) void ln_kernel(const u16* __restrict__ y,
                                                 const float* __restrict__ g,
                                                 const float* __restrict__ bt,
                                                 float* __restrict__ out) {
  const int row = blockIdx.x;
  const u16* yr = y + (size_t)row * HID;
  const int t = threadIdx.x;
  ushort4 u = *(const ushort4*)(yr + t * 4);
  float v0 = bf2f(u.x), v1 = bf2f(u.y), v2 = bf2f(u.z), v3 = bf2f(u.w);
  float s  = v0 + v1 + v2 + v3;
  float ss = v0 * v0 + v1 * v1 + v2 * v2 + v3 * v3;
#pragma unroll
  for (int m = 1; m < 64; m <<= 1) { s += __shfl_xor(s, m); ss += __shfl_xor(ss, m); }
  __shared__ float red[8];
  const int wave = t >> 6, lane = t & 63;
  if (lane == 0) { red[wave] = s; red[4 + wave] = ss; }
  __syncthreads();
  float st  = red[0] + red[1] + red[2] + red[3];
  float sst = red[4] + red[5] + red[6] + red[7];
  float mu  = st * (1.f / 1024.f);
  float var = sst * (1.f / 1024.f) - mu * mu;
  float inv = rsqrtf(var + 1e-5f);
  const int c = t * 4;
  float4 o;
  o.x = g[c + 0] * ((v0 - mu) * inv) + bt[c + 0];
  o.y = g[c + 1] * ((v1 - mu) * inv) + bt[c + 1];
  o.z = g[c + 2] * ((v2 - mu) * inv) + bt[c + 2];
  o.w = g[c + 3] * ((v3 - mu) * inv) + bt[c + 3];
  *(float4*)(out + (size_t)row * HID + c) = o;
}

// ---------------- launch ----------------
extern "C" void kernel_launch(void* const* d_in, const int* in_sizes, int n_in,
                              void* d_out, int out_size, void* d_ws, size_t ws_size,
                              hipStream_t stream) {
  const float* x     = (const float*)d_in[0];
  const float* Wq    = (const float*)d_in[1];
  const float* Wk    = (const float*)d_in[2];
  const float* Wv    = (const float*)d_in[3];
  const float* Wbeta = (const float*)d_in[4];
  const float* bbeta = (const float*)d_in[5];
  const float* Wo    = (const float*)d_in[6];
  const float* b_o   = (const float*)d_in[7];
  const float* ln_g  = (const float*)d_in[8];
  const float* ln_b  = (const float*)d_in[9];
  float* out = (float*)d_out;

  char* ws = (char*)d_ws;
  size_t off = 0;
  auto alloc = [&](size_t bytes) {
    char* p = ws + off; off += (bytes + 255) & ~(size_t)255; return p;
  };
  u16* xb   = (u16*)alloc((size_t)M * HID * 2);   // x bf16 (residual for EPI2)
  u16* kbuf = (u16*)alloc((size_t)M * HID * 2);   // k; reused as y after scans
  u16* obuf = (u16*)alloc((size_t)M * HID * 2);
  u16* WkT  = (u16*)alloc((size_t)HID * HID * 2);
  u16* WoT  = (u16*)alloc((size_t)HID * HID * 2);
  u16* WsT  = (u16*)alloc((size_t)128 * HID * 2);
  float* sq_t = (float*)alloc((size_t)64 * SEQ * 4);
  float* sv_t = (float*)alloc((size_t)64 * SEQ * 4);
  float* sb_t = (float*)alloc((size_t)64 * SEQ * 4);
  float* Pbuf = (float*)alloc((size_t)4096 * 4);
  float* Rloc = (float*)alloc((size_t)4096 * 64 * 4);
  float* Rin  = (float*)alloc((size_t)4096 * 64 * 4);
  u16* ybuf = kbuf;  // kbuf dead (as k) after scan_apply

  cast_x_kernel<<<8192, 256, 0, stream>>>((const float4*)x, (uint4*)xb);
  transpose_cast<<<dim3(32, 32, 2), 256, 0, stream>>>(Wk, Wo, WkT, WoT);
  build_wsum<<<512, 256, 0, stream>>>(Wq, Wv, Wbeta, WsT);

  // GEMM1 merged: 128 bm x (8 WkT col-blocks + 1 skinny WsT block) = 1152 blocks
  gemm_bf16<128, 128, 2, 2, 3><<<(M / 128) * 9, 256, 0, stream>>>(
      xb, WkT, WsT, HID, KD, 9, kbuf, nullptr, bbeta, sq_t, sv_t, sb_t);

  scan_chunks<<<1024, 256, 0, stream>>>(kbuf, sv_t, sb_t, Pbuf, Rloc);
  scan_prefix<<<64, 64, 0, stream>>>(Pbuf, Rloc, Rin);
  scan_apply<<<1024, 256, 0, stream>>>(kbuf, sq_t, sv_t, sb_t, Rin, obuf);

  // EPI2: y = bf16(xb + obuf@WoT + b_o), written over kbuf (k is dead now)
  gemm_bf16<128, 128, 2, 2, 2><<<(M / 128) * (HID / 128), 256, 0, stream>>>(
      obuf, WoT, nullptr, HID, KD, HID / 128, ybuf, xb, b_o, nullptr, nullptr, nullptr);

  ln_kernel<<<M, 256, 0, stream>>>(ybuf, ln_g, ln_b, out);
}

// Round 6
// 168.891 us; speedup vs baseline: 1.2409x; 1.2409x over previous
//
#include <hip/hip_runtime.h>
#include <hip/hip_bf16.h>

typedef unsigned short u16;
typedef unsigned int   u32;
typedef u32 __attribute__((address_space(1))) gas_u32;
typedef u32 __attribute__((address_space(3))) las_u32;
typedef __bf16 bf16x8 __attribute__((ext_vector_type(8)));
typedef float  f32x4  __attribute__((ext_vector_type(4)));

constexpr int BATCH = 4, SEQ = 4096, HID = 1024, NH = 16, DH = 64;
constexpr int M  = BATCH * SEQ;   // 16384 rows
constexpr int KD = HID;           // 1024 (K of all GEMMs)

__device__ __forceinline__ u16 f2bf(float f) {
  __hip_bfloat16 h = __float2bfloat16(f);
  u16 u; __builtin_memcpy(&u, &h, 2); return u;
}
__device__ __forceinline__ float bf2f(u16 u) {
  u32 x = ((u32)u) << 16; float f; __builtin_memcpy(&f, &x, 4); return f;
}

// ---------------- prep kernels ----------------

__global__ __launch_bounds__(256) void cast_x_kernel(const float4* __restrict__ x,
                                                     uint4* __restrict__ xb) {
  int i = blockIdx.x * 256 + threadIdx.x;
  float4 a = x[2 * i], b = x[2 * i + 1];
  uint4 o;
  o.x = (u32)f2bf(a.x) | ((u32)f2bf(a.y) << 16);
  o.y = (u32)f2bf(a.z) | ((u32)f2bf(a.w) << 16);
  o.z = (u32)f2bf(b.x) | ((u32)f2bf(b.y) << 16);
  o.w = (u32)f2bf(b.z) | ((u32)f2bf(b.w) << 16);
  xb[i] = o;
}

__global__ __launch_bounds__(256) void transpose_cast(const float* __restrict__ Wk,
                                                      const float* __restrict__ Wo,
                                                      u16* __restrict__ WkT,
                                                      u16* __restrict__ WoT) {
  __shared__ float tile[32][33];
  const float* src = blockIdx.z ? Wo : Wk;
  u16* dst = blockIdx.z ? WoT : WkT;
  int bx = blockIdx.x * 32, by = blockIdx.y * 32;
  int tx = threadIdx.x & 31, ty = threadIdx.x >> 5;
#pragma unroll
  for (int i = 0; i < 4; i++)
    tile[ty + i * 8][tx] = src[(size_t)(by + ty + i * 8) * HID + bx + tx];
  __syncthreads();
#pragma unroll
  for (int i = 0; i < 4; i++)
    dst[(size_t)(bx + ty + i * 8) * HID + by + tx] = f2bf(tile[tx][ty + i * 8]);
}

// WsT (64 x 1024 bf16): rows 0..15 colsum(Wq)/head, 16..31 colsum(Wv), 32..47 Wbeta, 48..63 zero
__global__ __launch_bounds__(256) void build_wsum(const float* __restrict__ Wq,
                                                  const float* __restrict__ Wv,
                                                  const float* __restrict__ Wbeta,
                                                  u16* __restrict__ WsT) {
  int tid = blockIdx.x * 256 + threadIdx.x;   // 65536
  int c = tid >> 10, kk = tid & 1023;
  float s = 0.f;
  if (c < 16)      { for (int d = 0; d < DH; d++) s += Wq[(size_t)kk * HID + c * DH + d]; }
  else if (c < 32) { for (int d = 0; d < DH; d++) s += Wv[(size_t)kk * HID + (c - 16) * DH + d]; }
  else if (c < 48) { s = Wbeta[(size_t)kk * NH + (c - 32)]; }
  WsT[(size_t)c * HID + kk] = f2bf(s);
}

// ============ 256x256 8-wave phase-pipelined MFMA GEMM (T2+T3+T4+T5) ============
// C(MxN) = A(MxK) * Bt(NxK)^T, K=1024, BK=64, 512 threads (8 waves, 2M x 4N).
// LDS: 2 dbuf x (A 256x64 + B 256x64) bf16 = 128 KiB -> 1 block/CU.
// Per K-tile: 4 phases (C-quadrant qm,qn), 16 MFMA each; each phase also
// stages 2 quarters of the NEXT K-tile.
//
// R5 race fix: vmcnt is PER-WAVE but LDS tiles are filled by ALL waves, so
// every counted wait must be followed by an s_barrier BEFORE any dependent
// ds_read (wait -> barrier -> read). Waits sit at END of ph1 (vmcnt(4),
// completes current tile's late A-quarters cA1,cA3 before ph2 reads them)
// and END of ph3 (vmcnt(2), completes next tile's A0,A2,B0-3 before the
// next K-tile's ph0; leaves nA1,nA3 in flight). Never drains to 0 in-loop.
//
// T2 swizzle: LDS stays LINEAR [256][64]; lane's GLOBAL source col-group is
// pre-swizzled (s ^ (row&7)) and ds_read applies the same involution.

__device__ __forceinline__ void stage_quarter(const u16* __restrict__ Gk,
                                              int q, u16* lds_tile, int tid, int wave) {
  const int row = q * 64 + (tid >> 3);          // 64 rows per quarter
  const int s = tid & 7;                        // 16B col-group
  const u16* g = Gk + (size_t)row * KD + (size_t)((s ^ (row & 7)) << 3);
  u16* l = lds_tile + q * 4096 + wave * 512;    // wave-uniform LDS base, lanes +16B
  __builtin_amdgcn_global_load_lds((const gas_u32*)g, (las_u32*)l, 16, 0, 0);
}

__device__ __forceinline__ const bf16x8* lds_frag(const u16* lds_tile, int row, int cg) {
  return (const bf16x8*)(lds_tile + ((size_t)row << 6) + (size_t)((cg ^ (row & 7)) << 3));
}

// EPI 0: C = bf16(acc). EPI 2: C = bf16(xres + acc + bias).
template <int EPI>
__global__ __launch_bounds__(512) void gemm256(
    const u16* __restrict__ A, const u16* __restrict__ Bt, int N,
    u16* __restrict__ Cb, const u16* __restrict__ xres, const float* __restrict__ bias) {
  constexpr int BK = 64, NT = KD / BK;  // 16 K-tiles
  __shared__ u16 lds[2][2][16384];      // [buf][A=0/B=1][256*64]
  const int tid = threadIdx.x, wave = tid >> 6, lane = tid & 63;
  const int wm = wave >> 2, wn = wave & 3;
  const int r16 = lane & 15, hi = lane >> 4;
  const int nbn = N >> 8;
  const int bm = (int)blockIdx.x / nbn, bn = (int)blockIdx.x % nbn;
  const u16* Abase = A + (size_t)bm * 256 * KD;
  const u16* Bbase = Bt + (size_t)bn * 256 * KD;

  f32x4 acc[8][4] = {};

  // prologue: stage tile 0 into buf0. Oldest-6 = A0,A2,B0..B3 (needed at ph0);
  // A1,A3 stay in flight, completed by kt0-ph1's vmcnt(4).
  {
    u16* la = &lds[0][0][0]; u16* lb = &lds[0][1][0];
    stage_quarter(Abase, 0, la, tid, wave);
    stage_quarter(Abase, 2, la, tid, wave);
    stage_quarter(Bbase, 0, lb, tid, wave);
    stage_quarter(Bbase, 1, lb, tid, wave);
    stage_quarter(Bbase, 2, lb, tid, wave);
    stage_quarter(Bbase, 3, lb, tid, wave);
    stage_quarter(Abase, 1, la, tid, wave);
    stage_quarter(Abase, 3, la, tid, wave);
  }
  asm volatile("s_waitcnt vmcnt(2)" ::: "memory");
  __builtin_amdgcn_s_barrier();

  for (int kt = 0; kt < NT; ++kt) {
    const int cur = kt & 1;
    const u16* la = &lds[cur][0][0];
    const u16* lb = &lds[cur][1][0];
    u16* na = &lds[cur ^ 1][0][0];
    u16* nb = &lds[cur ^ 1][1][0];
    const int knext = ((kt + 1) & (NT - 1)) * BK;   // wraps to 0 on last iter (dead data)
    const u16* An = Abase + knext;
    const u16* Bn = Bbase + knext;
#pragma unroll
    for (int ph = 0; ph < 4; ++ph) {
      const int qm = ph >> 1, qn = ph & 1;
      // issue 2 staging quarters for next tile (into the buffer NOT being read)
      if (ph == 0)      { stage_quarter(An, 0, na, tid, wave); stage_quarter(An, 2, na, tid, wave); }
      else if (ph == 1) { stage_quarter(Bn, 0, nb, tid, wave); stage_quarter(Bn, 1, nb, tid, wave); }
      else if (ph == 2) { stage_quarter(Bn, 2, nb, tid, wave); stage_quarter(Bn, 3, nb, tid, wave); }
      else              { stage_quarter(An, 1, na, tid, wave); stage_quarter(An, 3, na, tid, wave); }
      // ds_read 12 fragments for this quadrant (data guaranteed by the
      // wait+barrier pair executed in an EARLIER phase by all waves)
      bf16x8 af[4][2], bfr[2][2];
#pragma unroll
      for (int f = 0; f < 4; ++f) {
        const int row = wm * 128 + (qm * 4 + f) * 16 + r16;
#pragma unroll
        for (int kk = 0; kk < 2; ++kk)
          af[f][kk] = *lds_frag(la, row, kk * 4 + hi);
      }
#pragma unroll
      for (int f = 0; f < 2; ++f) {
        const int rowb = wn * 64 + (qn * 2 + f) * 16 + r16;
#pragma unroll
        for (int kk = 0; kk < 2; ++kk)
          bfr[f][kk] = *lds_frag(lb, rowb, kk * 4 + hi);
      }
      __builtin_amdgcn_s_barrier();
      asm volatile("s_waitcnt lgkmcnt(0)" ::: "memory");
      __builtin_amdgcn_sched_barrier(0);          // rule #18: stop MFMA hoisting
      __builtin_amdgcn_s_setprio(1);
#pragma unroll
      for (int f = 0; f < 4; ++f)
#pragma unroll
        for (int g2 = 0; g2 < 2; ++g2)
#pragma unroll
          for (int kk = 0; kk < 2; ++kk)
            acc[qm * 4 + f][qn * 2 + g2] = __builtin_amdgcn_mfma_f32_16x16x32_bf16(
                af[f][kk], bfr[g2][kk], acc[qm * 4 + f][qn * 2 + g2], 0, 0, 0);
      __builtin_amdgcn_s_setprio(0);
      // T4 counted waits BEFORE the closing barrier (wait -> barrier -> read):
      if (ph == 1) { asm volatile("s_waitcnt vmcnt(4)" ::: "memory"); }  // completes cA1,cA3
      if (ph == 3) { asm volatile("s_waitcnt vmcnt(2)" ::: "memory"); }  // completes nA0,nA2,nB0-3
      __builtin_amdgcn_s_barrier();
    }
  }
  // drain in-flight LDS-DMA before workgroup teardown
  asm volatile("s_waitcnt vmcnt(0)" ::: "memory");

  // epilogue
#pragma unroll
  for (int fm = 0; fm < 8; ++fm) {
#pragma unroll
    for (int fn = 0; fn < 4; ++fn) {
      const int col = bn * 256 + wn * 64 + fn * 16 + r16;
#pragma unroll
      for (int j = 0; j < 4; ++j) {
        const int row = bm * 256 + wm * 128 + fm * 16 + hi * 4 + j;
        float v = acc[fm][fn][j];
        if constexpr (EPI == 2) v += bf2f(xres[(size_t)row * N + col]) + bias[col];
        Cb[(size_t)row * N + col] = f2bf(v);
      }
    }
  }
}

// ---------------- skinny head-stat GEMM (m97 structure, 128x64) ----------------
__global__ __launch_bounds__(256) void gemm_skinny(
    const u16* __restrict__ A, const u16* __restrict__ Bt,
    const float* __restrict__ bias, float* __restrict__ sq,
    float* __restrict__ sv, float* __restrict__ sb) {
  constexpr int BM = 128, BN = 64, BK = 64;
  constexpr int WTM = 32, FM = 2, FN = 4;   // 4 waves x (32 rows x 64 cols)
  __shared__ u16 As[BM * BK];
  __shared__ u16 Bs[BN * BK];
  const int tid = threadIdx.x, wave = tid >> 6, lane = tid & 63;
  const int bm = blockIdx.x;
  const int r16 = lane & 15, hi = lane >> 4;
  const int rsub = lane >> 3, csub = (lane & 7) * 8;
  f32x4 acc[FM][FN] = {};
  const u16* Ab = A + (size_t)bm * BM * KD;

  for (int kt = 0; kt < KD; kt += BK) {
#pragma unroll
    for (int i = 0; i < 4; i++) {
      int slot = wave * 4 + i;
      const u16* g = Ab + (size_t)(slot * 8 + rsub) * KD + kt + csub;
      __builtin_amdgcn_global_load_lds((const gas_u32*)g, (las_u32*)(As + slot * 512), 16, 0, 0);
    }
#pragma unroll
    for (int i = 0; i < 2; i++) {
      int slot = wave * 2 + i;
      const u16* g = Bt + (size_t)(slot * 8 + rsub) * KD + kt + csub;
      __builtin_amdgcn_global_load_lds((const gas_u32*)g, (las_u32*)(Bs + slot * 512), 16, 0, 0);
    }
    __syncthreads();
#pragma unroll
    for (int kk = 0; kk < 2; kk++) {
      bf16x8 af[FM], bfr[FN];
#pragma unroll
      for (int f = 0; f < FM; f++)
        af[f] = *(const bf16x8*)(As + (wave * WTM + f * 16 + r16) * BK + kk * 32 + hi * 8);
#pragma unroll
      for (int f = 0; f < FN; f++)
        bfr[f] = *(const bf16x8*)(Bs + (f * 16 + r16) * BK + kk * 32 + hi * 8);
#pragma unroll
      for (int fm = 0; fm < FM; fm++)
#pragma unroll
        for (int fn = 0; fn < FN; fn++)
          acc[fm][fn] = __builtin_amdgcn_mfma_f32_16x16x32_bf16(af[fm], bfr[fn], acc[fm][fn], 0, 0, 0);
    }
    __syncthreads();
  }

#pragma unroll
  for (int fm = 0; fm < FM; fm++) {
#pragma unroll
    for (int fn = 0; fn < FN; fn++) {
      const int col = fn * 16 + r16;
#pragma unroll
      for (int j = 0; j < 4; j++) {
        const int row = bm * BM + wave * WTM + fm * 16 + hi * 4 + j;
        const int b = row >> 12, t = row & 4095;
        float v = acc[fm][fn][j];
        if (col < 16)      sq[((size_t)(b * 16 + col)) * SEQ + t] = v;
        else if (col < 32) sv[((size_t)(b * 16 + col - 16)) * SEQ + t] = v;
        else if (col < 48) {
          float z = v + bias[col - 32];
          sb[((size_t)(b * 16 + col - 32)) * SEQ + t] = 1.f / (1.f + __expf(-z));
        }
      }
    }
  }
}

// ---------------- chunked scan: r_t = b_t*r_{t-1} + k_t*vsum_t ----------------

__global__ __launch_bounds__(256) void scan_chunks(const u16* __restrict__ kbuf,
                                                   const float* __restrict__ sv_t,
                                                   const float* __restrict__ sb_t,
                                                   float* __restrict__ Pbuf,
                                                   float* __restrict__ Rloc) {
  const int wave = threadIdx.x >> 6, lane = threadIdx.x & 63;
  const int gid = blockIdx.x * 4 + wave;
  const int seq = gid >> 6, chunk = gid & 63;
  const int b = seq >> 4, h = seq & 15;
  const int t0 = chunk * 64;
  const float bet = sb_t[(size_t)seq * SEQ + t0 + lane];
  const float vs  = sv_t[(size_t)seq * SEQ + t0 + lane];
  const u16* kp = kbuf + ((size_t)(b * SEQ + t0)) * HID + h * DH + lane;
  float r = 0.f, P = 1.f;
#pragma unroll
  for (int tt = 0; tt < 64; tt += 8) {
    u16 kr[8];
#pragma unroll
    for (int j = 0; j < 8; j++) kr[j] = kp[(size_t)(tt + j) * HID];
#pragma unroll
    for (int j = 0; j < 8; j++) {
      float bt = __shfl(bet, tt + j);
      float vt = __shfl(vs, tt + j);
      r = fmaf(r, bt, bf2f(kr[j]) * vt);
      P *= bt;
    }
  }
  Rloc[(size_t)gid * 64 + lane] = r;
  if (lane == 0) Pbuf[gid] = P;
}

__global__ __launch_bounds__(64) void scan_prefix(const float* __restrict__ Pbuf,
                                                  const float* __restrict__ Rloc,
                                                  float* __restrict__ Rin) {
  const int seq = blockIdx.x, lane = threadIdx.x;
  const float* pp = Pbuf + seq * 64;
  const float* rl = Rloc + (size_t)seq * 64 * 64 + lane;
  float* ri = Rin + (size_t)seq * 64 * 64 + lane;
  float rin = 0.f;
#pragma unroll
  for (int c0 = 0; c0 < 64; c0 += 8) {
    float P[8], L[8];
#pragma unroll
    for (int j = 0; j < 8; j++) { P[j] = pp[c0 + j]; L[j] = rl[(size_t)(c0 + j) * 64]; }
#pragma unroll
    for (int j = 0; j < 8; j++) {
      ri[(size_t)(c0 + j) * 64] = rin;
      rin = fmaf(P[j], rin, L[j]);
    }
  }
}

__global__ __launch_bounds__(256) void scan_apply(const u16* __restrict__ kbuf,
                                                  const float* __restrict__ sq_t,
                                                  const float* __restrict__ sv_t,
                                                  const float* __restrict__ sb_t,
                                                  const float* __restrict__ Rin,
                                                  u16* __restrict__ obuf) {
  const int wave = threadIdx.x >> 6, lane = threadIdx.x & 63;
  const int gid = blockIdx.x * 4 + wave;
  const int seq = gid >> 6, chunk = gid & 63;
  const int b = seq >> 4, h = seq & 15;
  const int t0 = chunk * 64;
  const float bet = sb_t[(size_t)seq * SEQ + t0 + lane];
  const float vs  = sv_t[(size_t)seq * SEQ + t0 + lane];
  const float qs  = sq_t[(size_t)seq * SEQ + t0 + lane];
  const u16* kp = kbuf + ((size_t)(b * SEQ + t0)) * HID + h * DH + lane;
  u16* op = obuf + ((size_t)(b * SEQ + t0)) * HID + h * DH + lane;
  float r = Rin[(size_t)gid * 64 + lane];
#pragma unroll
  for (int tt = 0; tt < 64; tt += 8) {
    u16 kr[8];
#pragma unroll
    for (int j = 0; j < 8; j++) kr[j] = kp[(size_t)(tt + j) * HID];
#pragma unroll
    for (int j = 0; j < 8; j++) {
      float bt = __shfl(bet, tt + j);
      float vt = __shfl(vs, tt + j);
      float qt = __shfl(qs, tt + j);
      r = fmaf(r, bt, bf2f(kr[j]) * vt);
      op[(size_t)(tt + j) * HID] = f2bf(qt * r);
    }
  }
}

// ---------------- LayerNorm (row per block) ----------------
__global__ __launch_bounds__(256) void ln_kernel(const u16* __restrict__ y,
                                                 const float* __restrict__ g,
                                                 const float* __restrict__ bt,
                                                 float* __restrict__ out) {
  const int row = blockIdx.x;
  const u16* yr = y + (size_t)row * HID;
  const int t = threadIdx.x;
  ushort4 u = *(const ushort4*)(yr + t * 4);
  float v0 = bf2f(u.x), v1 = bf2f(u.y), v2 = bf2f(u.z), v3 = bf2f(u.w);
  float s  = v0 + v1 + v2 + v3;
  float ss = v0 * v0 + v1 * v1 + v2 * v2 + v3 * v3;
#pragma unroll
  for (int m = 1; m < 64; m <<= 1) { s += __shfl_xor(s, m); ss += __shfl_xor(ss, m); }
  __shared__ float red[8];
  const int wave = t >> 6, lane = t & 63;
  if (lane == 0) { red[wave] = s; red[4 + wave] = ss; }
  __syncthreads();
  float st  = red[0] + red[1] + red[2] + red[3];
  float sst = red[4] + red[5] + red[6] + red[7];
  float mu  = st * (1.f / 1024.f);
  float var = sst * (1.f / 1024.f) - mu * mu;
  float inv = rsqrtf(var + 1e-5f);
  const int c = t * 4;
  float4 o;
  o.x = g[c + 0] * ((v0 - mu) * inv) + bt[c + 0];
  o.y = g[c + 1] * ((v1 - mu) * inv) + bt[c + 1];
  o.z = g[c + 2] * ((v2 - mu) * inv) + bt[c + 2];
  o.w = g[c + 3] * ((v3 - mu) * inv) + bt[c + 3];
  *(float4*)(out + (size_t)row * HID + c) = o;
}

// ---------------- launch ----------------
extern "C" void kernel_launch(void* const* d_in, const int* in_sizes, int n_in,
                              void* d_out, int out_size, void* d_ws, size_t ws_size,
                              hipStream_t stream) {
  const float* x     = (const float*)d_in[0];
  const float* Wq    = (const float*)d_in[1];
  const float* Wk    = (const float*)d_in[2];
  const float* Wv    = (const float*)d_in[3];
  const float* Wbeta = (const float*)d_in[4];
  const float* bbeta = (const float*)d_in[5];
  const float* Wo    = (const float*)d_in[6];
  const float* b_o   = (const float*)d_in[7];
  const float* ln_g  = (const float*)d_in[8];
  const float* ln_b  = (const float*)d_in[9];
  float* out = (float*)d_out;

  char* ws = (char*)d_ws;
  size_t off = 0;
  auto alloc = [&](size_t bytes) {
    char* p = ws + off; off += (bytes + 255) & ~(size_t)255; return p;
  };
  u16* xb   = (u16*)alloc((size_t)M * HID * 2);   // x bf16 (residual for EPI2)
  u16* kbuf = (u16*)alloc((size_t)M * HID * 2);   // k; reused as y after scans
  u16* obuf = (u16*)alloc((size_t)M * HID * 2);
  u16* WkT  = (u16*)alloc((size_t)HID * HID * 2);
  u16* WoT  = (u16*)alloc((size_t)HID * HID * 2);
  u16* WsT  = (u16*)alloc((size_t)64 * HID * 2);
  float* sq_t = (float*)alloc((size_t)64 * SEQ * 4);
  float* sv_t = (float*)alloc((size_t)64 * SEQ * 4);
  float* sb_t = (float*)alloc((size_t)64 * SEQ * 4);
  float* Pbuf = (float*)alloc((size_t)4096 * 4);
  float* Rloc = (float*)alloc((size_t)4096 * 64 * 4);
  float* Rin  = (float*)alloc((size_t)4096 * 64 * 4);
  u16* ybuf = kbuf;  // kbuf dead (as k) after scan_apply

  cast_x_kernel<<<8192, 256, 0, stream>>>((const float4*)x, (uint4*)xb);
  transpose_cast<<<dim3(32, 32, 2), 256, 0, stream>>>(Wk, Wo, WkT, WoT);
  build_wsum<<<256, 256, 0, stream>>>(Wq, Wv, Wbeta, WsT);

  // skinny head-stats (re-reads xb; small)
  gemm_skinny<<<M / 128, 256, 0, stream>>>(xb, WsT, bbeta, sq_t, sv_t, sb_t);

  // k = xb @ WkT^T  (256x256 phase-pipelined, 64x4 = 256 blocks = 1/CU)
  gemm256<0><<<(M / 256) * (HID / 256), 512, 0, stream>>>(
      xb, WkT, HID, kbuf, nullptr, nullptr);

  scan_chunks<<<1024, 256, 0, stream>>>(kbuf, sv_t, sb_t, Pbuf, Rloc);
  scan_prefix<<<64, 64, 0, stream>>>(Pbuf, Rloc, Rin);
  scan_apply<<<1024, 256, 0, stream>>>(kbuf, sq_t, sv_t, sb_t, Rin, obuf);

  // y = bf16(xb + obuf @ WoT^T + b_o), written over kbuf (k dead)
  gemm256<2><<<(M / 256) * (HID / 256), 512, 0, stream>>>(
      obuf, WoT, HID, ybuf, xb, b_o);

  ln_kernel<<<M, 256, 0, stream>>>(ybuf, ln_g, ln_b, out);
}

// Round 7
// 163.141 us; speedup vs baseline: 1.2847x; 1.0352x over previous
//
#include <hip/hip_runtime.h>
#include <hip/hip_bf16.h>

typedef unsigned short u16;
typedef unsigned int   u32;
typedef u32 __attribute__((address_space(1))) gas_u32;
typedef u32 __attribute__((address_space(3))) las_u32;
typedef __bf16 bf16x8 __attribute__((ext_vector_type(8)));
typedef float  f32x4  __attribute__((ext_vector_type(4)));

constexpr int BATCH = 4, SEQ = 4096, HID = 1024, NH = 16, DH = 64;
constexpr int M  = BATCH * SEQ;   // 16384 rows
constexpr int KD = HID;           // 1024 (K of all GEMMs)

__device__ __forceinline__ u16 f2bf(float f) {
  __hip_bfloat16 h = __float2bfloat16(f);
  u16 u; __builtin_memcpy(&u, &h, 2); return u;
}
__device__ __forceinline__ float bf2f(u16 u) {
  u32 x = ((u32)u) << 16; float f; __builtin_memcpy(&f, &x, 4); return f;
}

// ---------------- prep kernels ----------------

__global__ __launch_bounds__(256) void cast_x_kernel(const float4* __restrict__ x,
                                                     uint4* __restrict__ xb) {
  int i = blockIdx.x * 256 + threadIdx.x;
  float4 a = x[2 * i], b = x[2 * i + 1];
  uint4 o;
  o.x = (u32)f2bf(a.x) | ((u32)f2bf(a.y) << 16);
  o.y = (u32)f2bf(a.z) | ((u32)f2bf(a.w) << 16);
  o.z = (u32)f2bf(b.x) | ((u32)f2bf(b.y) << 16);
  o.w = (u32)f2bf(b.z) | ((u32)f2bf(b.w) << 16);
  xb[i] = o;
}

__global__ __launch_bounds__(256) void transpose_cast(const float* __restrict__ Wk,
                                                      const float* __restrict__ Wo,
                                                      u16* __restrict__ WkT,
                                                      u16* __restrict__ WoT) {
  __shared__ float tile[32][33];
  const float* src = blockIdx.z ? Wo : Wk;
  u16* dst = blockIdx.z ? WoT : WkT;
  int bx = blockIdx.x * 32, by = blockIdx.y * 32;
  int tx = threadIdx.x & 31, ty = threadIdx.x >> 5;
#pragma unroll
  for (int i = 0; i < 4; i++)
    tile[ty + i * 8][tx] = src[(size_t)(by + ty + i * 8) * HID + bx + tx];
  __syncthreads();
#pragma unroll
  for (int i = 0; i < 4; i++)
    dst[(size_t)(bx + ty + i * 8) * HID + by + tx] = f2bf(tile[tx][ty + i * 8]);
}

// WsT (64 x 1024 bf16): rows 0..15 colsum(Wq)/head, 16..31 colsum(Wv), 32..47 Wbeta, 48..63 zero
__global__ __launch_bounds__(256) void build_wsum(const float* __restrict__ Wq,
                                                  const float* __restrict__ Wv,
                                                  const float* __restrict__ Wbeta,
                                                  u16* __restrict__ WsT) {
  int tid = blockIdx.x * 256 + threadIdx.x;   // 65536
  int c = tid >> 10, kk = tid & 1023;
  float s = 0.f;
  if (c < 16)      { for (int d = 0; d < DH; d++) s += Wq[(size_t)kk * HID + c * DH + d]; }
  else if (c < 32) { for (int d = 0; d < DH; d++) s += Wv[(size_t)kk * HID + (c - 16) * DH + d]; }
  else if (c < 48) { s = Wbeta[(size_t)kk * NH + (c - 32)]; }
  WsT[(size_t)c * HID + kk] = f2bf(s);
}

// ============ 256x256 8-wave phase-pipelined MFMA GEMM (T2+T3+T4+T5) ============
// C(MxN) = A(MxK) * Bt(NxK)^T, K=1024, BK=64, 512 threads (8 waves, 2M x 4N).
// LDS: 2 dbuf x (A 256x64 + B 256x64) bf16 = 128 KiB -> 1 block/CU.
//
// R6->R7: register-blocked fragments. Phases are (m-half x kk-slice); the
// wave's B-frags (its 64-col n-stripe) are read ONCE per kk and held in
// bF[4][2] across phases; A-frags read once each. 24 ds_read_b128 per
// K-tile (was 48); distribution 8/8/4/4. MFMA pipe becomes critical resource.
//
// Sync schedule (R5 race fix, unchanged): vmcnt is PER-WAVE while tiles are
// filled by ALL waves -> every counted wait precedes an s_barrier BEFORE any
// dependent ds_read. Waits: end-ph1 vmcnt(4) (completes current A1,A3 before
// ph2 reads), end-ph3 vmcnt(2) (completes next A0,A2,B0-3; leaves nA1,nA3).
// Phase reads: ph0/ph1 -> A0/A2 + B (complete at tile entry); ph2/ph3 ->
// A1/A3 (complete after ph1 wait+barrier). Never drains to 0 in-loop.
//
// T2 swizzle: LDS stays LINEAR [256][64]; lane's GLOBAL source col-group is
// pre-swizzled (s ^ (row&7)) and ds_read applies the same involution.

__device__ __forceinline__ void stage_quarter(const u16* __restrict__ Gk,
                                              int q, u16* lds_tile, int tid, int wave) {
  const int row = q * 64 + (tid >> 3);          // 64 rows per quarter
  const int s = tid & 7;                        // 16B col-group
  const u16* g = Gk + (size_t)row * KD + (size_t)((s ^ (row & 7)) << 3);
  u16* l = lds_tile + q * 4096 + wave * 512;    // wave-uniform LDS base, lanes +16B
  __builtin_amdgcn_global_load_lds((const gas_u32*)g, (las_u32*)l, 16, 0, 0);
}

__device__ __forceinline__ const bf16x8* lds_frag(const u16* lds_tile, int row, int cg) {
  return (const bf16x8*)(lds_tile + ((size_t)row << 6) + (size_t)((cg ^ (row & 7)) << 3));
}

// EPI 0: C = bf16(acc). EPI 2: C = bf16(xres + acc + bias).
template <int EPI>
__global__ __launch_bounds__(512) void gemm256(
    const u16* __restrict__ A, const u16* __restrict__ Bt, int N,
    u16* __restrict__ Cb, const u16* __restrict__ xres, const float* __restrict__ bias) {
  constexpr int BK = 64, NT = KD / BK;  // 16 K-tiles
  __shared__ u16 lds[2][2][16384];      // [buf][A=0/B=1][256*64]
  const int tid = threadIdx.x, wave = tid >> 6, lane = tid & 63;
  const int wm = wave >> 2, wn = wave & 3;
  const int r16 = lane & 15, hi = lane >> 4;
  const int nbn = N >> 8;
  const int bm = (int)blockIdx.x / nbn, bn = (int)blockIdx.x % nbn;
  const u16* Abase = A + (size_t)bm * 256 * KD;
  const u16* Bbase = Bt + (size_t)bn * 256 * KD;

  f32x4 acc[8][4] = {};

  // prologue: stage tile 0 into buf0. Oldest-6 = A0,A2,B0..B3 (needed at ph0);
  // A1,A3 stay in flight, completed by kt0-ph1's vmcnt(4).
  {
    u16* la = &lds[0][0][0]; u16* lb = &lds[0][1][0];
    stage_quarter(Abase, 0, la, tid, wave);
    stage_quarter(Abase, 2, la, tid, wave);
    stage_quarter(Bbase, 0, lb, tid, wave);
    stage_quarter(Bbase, 1, lb, tid, wave);
    stage_quarter(Bbase, 2, lb, tid, wave);
    stage_quarter(Bbase, 3, lb, tid, wave);
    stage_quarter(Abase, 1, la, tid, wave);
    stage_quarter(Abase, 3, la, tid, wave);
  }
  asm volatile("s_waitcnt vmcnt(2)" ::: "memory");
  __builtin_amdgcn_s_barrier();

  for (int kt = 0; kt < NT; ++kt) {
    const int cur = kt & 1;
    const u16* la = &lds[cur][0][0];
    const u16* lb = &lds[cur][1][0];
    u16* na = &lds[cur ^ 1][0][0];
    u16* nb = &lds[cur ^ 1][1][0];
    const int knext = ((kt + 1) & (NT - 1)) * BK;   // wraps to 0 on last iter (dead data)
    const u16* An = Abase + knext;
    const u16* Bn = Bbase + knext;

    bf16x8 bF[4][2];   // wave's n-stripe B fragments, persistent across phases
#pragma unroll
    for (int ph = 0; ph < 4; ++ph) {
      const int mh = ph >> 1;     // m-half: ph0,1 -> rows +0..63; ph2,3 -> +64..127
      const int kk = ph & 1;      // K-slice of 32 within the 64-wide tile
      // issue 2 staging quarters for next tile (into the buffer NOT being read)
      if (ph == 0)      { stage_quarter(An, 0, na, tid, wave); stage_quarter(An, 2, na, tid, wave); }
      else if (ph == 1) { stage_quarter(Bn, 0, nb, tid, wave); stage_quarter(Bn, 1, nb, tid, wave); }
      else if (ph == 2) { stage_quarter(Bn, 2, nb, tid, wave); stage_quarter(Bn, 3, nb, tid, wave); }
      else              { stage_quarter(An, 1, na, tid, wave); stage_quarter(An, 3, na, tid, wave); }
      // ds_read: 4 A-frags (this m-half, this kk); B-frags only on ph0/ph1
      bf16x8 aF[4];
#pragma unroll
      for (int f = 0; f < 4; ++f)
        aF[f] = *lds_frag(la, wm * 128 + mh * 64 + f * 16 + r16, kk * 4 + hi);
      if (ph < 2) {
#pragma unroll
        for (int g = 0; g < 4; ++g)
          bF[g][kk] = *lds_frag(lb, wn * 64 + g * 16 + r16, kk * 4 + hi);
      }
      __builtin_amdgcn_s_barrier();
      asm volatile("s_waitcnt lgkmcnt(0)" ::: "memory");
      __builtin_amdgcn_sched_barrier(0);          // rule #18: stop MFMA hoisting
      __builtin_amdgcn_s_setprio(1);
#pragma unroll
      for (int f = 0; f < 4; ++f)
#pragma unroll
        for (int g = 0; g < 4; ++g)
          acc[mh * 4 + f][g] = __builtin_amdgcn_mfma_f32_16x16x32_bf16(
              aF[f], bF[g][kk], acc[mh * 4 + f][g], 0, 0, 0);
      __builtin_amdgcn_s_setprio(0);
      // T4 counted waits BEFORE the closing barrier (wait -> barrier -> read):
      if (ph == 1) { asm volatile("s_waitcnt vmcnt(4)" ::: "memory"); }  // completes cA1,cA3
      if (ph == 3) { asm volatile("s_waitcnt vmcnt(2)" ::: "memory"); }  // completes nA0,nA2,nB0-3
      __builtin_amdgcn_s_barrier();
    }
  }
  // drain in-flight LDS-DMA before workgroup teardown
  asm volatile("s_waitcnt vmcnt(0)" ::: "memory");

  // epilogue
#pragma unroll
  for (int fm = 0; fm < 8; ++fm) {
#pragma unroll
    for (int fn = 0; fn < 4; ++fn) {
      const int col = bn * 256 + wn * 64 + fn * 16 + r16;
#pragma unroll
      for (int j = 0; j < 4; ++j) {
        const int row = bm * 256 + wm * 128 + fm * 16 + hi * 4 + j;
        float v = acc[fm][fn][j];
        if constexpr (EPI == 2) v += bf2f(xres[(size_t)row * N + col]) + bias[col];
        Cb[(size_t)row * N + col] = f2bf(v);
      }
    }
  }
}

// ---------------- skinny head-stat GEMM (m97 structure, 128x64) ----------------
__global__ __launch_bounds__(256) void gemm_skinny(
    const u16* __restrict__ A, const u16* __restrict__ Bt,
    const float* __restrict__ bias, float* __restrict__ sq,
    float* __restrict__ sv, float* __restrict__ sb) {
  constexpr int BM = 128, BN = 64, BK = 64;
  constexpr int WTM = 32, FM = 2, FN = 4;   // 4 waves x (32 rows x 64 cols)
  __shared__ u16 As[BM * BK];
  __shared__ u16 Bs[BN * BK];
  const int tid = threadIdx.x, wave = tid >> 6, lane = tid & 63;
  const int bm = blockIdx.x;
  const int r16 = lane & 15, hi = lane >> 4;
  const int rsub = lane >> 3, csub = (lane & 7) * 8;
  f32x4 acc[FM][FN] = {};
  const u16* Ab = A + (size_t)bm * BM * KD;

  for (int kt = 0; kt < KD; kt += BK) {
#pragma unroll
    for (int i = 0; i < 4; i++) {
      int slot = wave * 4 + i;
      const u16* g = Ab + (size_t)(slot * 8 + rsub) * KD + kt + csub;
      __builtin_amdgcn_global_load_lds((const gas_u32*)g, (las_u32*)(As + slot * 512), 16, 0, 0);
    }
#pragma unroll
    for (int i = 0; i < 2; i++) {
      int slot = wave * 2 + i;
      const u16* g = Bt + (size_t)(slot * 8 + rsub) * KD + kt + csub;
      __builtin_amdgcn_global_load_lds((const gas_u32*)g, (las_u32*)(Bs + slot * 512), 16, 0, 0);
    }
    __syncthreads();
#pragma unroll
    for (int kk = 0; kk < 2; kk++) {
      bf16x8 af[FM], bfr[FN];
#pragma unroll
      for (int f = 0; f < FM; f++)
        af[f] = *(const bf16x8*)(As + (wave * WTM + f * 16 + r16) * BK + kk * 32 + hi * 8);
#pragma unroll
      for (int f = 0; f < FN; f++)
        bfr[f] = *(const bf16x8*)(Bs + (f * 16 + r16) * BK + kk * 32 + hi * 8);
#pragma unroll
      for (int fm = 0; fm < FM; fm++)
#pragma unroll
        for (int fn = 0; fn < FN; fn++)
          acc[fm][fn] = __builtin_amdgcn_mfma_f32_16x16x32_bf16(af[fm], bfr[fn], acc[fm][fn], 0, 0, 0);
    }
    __syncthreads();
  }

#pragma unroll
  for (int fm = 0; fm < FM; fm++) {
#pragma unroll
    for (int fn = 0; fn < FN; fn++) {
      const int col = fn * 16 + r16;
#pragma unroll
      for (int j = 0; j < 4; j++) {
        const int row = bm * BM + wave * WTM + fm * 16 + hi * 4 + j;
        const int b = row >> 12, t = row & 4095;
        float v = acc[fm][fn][j];
        if (col < 16)      sq[((size_t)(b * 16 + col)) * SEQ + t] = v;
        else if (col < 32) sv[((size_t)(b * 16 + col - 16)) * SEQ + t] = v;
        else if (col < 48) {
          float z = v + bias[col - 32];
          sb[((size_t)(b * 16 + col - 32)) * SEQ + t] = 1.f / (1.f + __expf(-z));
        }
      }
    }
  }
}

// ---------------- chunked scan: r_t = b_t*r_{t-1} + k_t*vsum_t ----------------

__global__ __launch_bounds__(256) void scan_chunks(const u16* __restrict__ kbuf,
                                                   const float* __restrict__ sv_t,
                                                   const float* __restrict__ sb_t,
                                                   float* __restrict__ Pbuf,
                                                   float* __restrict__ Rloc) {
  const int wave = threadIdx.x >> 6, lane = threadIdx.x & 63;
  const int gid = blockIdx.x * 4 + wave;
  const int seq = gid >> 6, chunk = gid & 63;
  const int b = seq >> 4, h = seq & 15;
  const int t0 = chunk * 64;
  const float bet = sb_t[(size_t)seq * SEQ + t0 + lane];
  const float vs  = sv_t[(size_t)seq * SEQ + t0 + lane];
  const u16* kp = kbuf + ((size_t)(b * SEQ + t0)) * HID + h * DH + lane;
  float r = 0.f, P = 1.f;
#pragma unroll
  for (int tt = 0; tt < 64; tt += 8) {
    u16 kr[8];
#pragma unroll
    for (int j = 0; j < 8; j++) kr[j] = kp[(size_t)(tt + j) * HID];
#pragma unroll
    for (int j = 0; j < 8; j++) {
      float bt = __shfl(bet, tt + j);
      float vt = __shfl(vs, tt + j);
      r = fmaf(r, bt, bf2f(kr[j]) * vt);
      P *= bt;
    }
  }
  Rloc[(size_t)gid * 64 + lane] = r;
  if (lane == 0) Pbuf[gid] = P;
}

__global__ __launch_bounds__(64) void scan_prefix(const float* __restrict__ Pbuf,
                                                  const float* __restrict__ Rloc,
                                                  float* __restrict__ Rin) {
  const int seq = blockIdx.x, lane = threadIdx.x;
  const float* pp = Pbuf + seq * 64;
  const float* rl = Rloc + (size_t)seq * 64 * 64 + lane;
  float* ri = Rin + (size_t)seq * 64 * 64 + lane;
  float rin = 0.f;
#pragma unroll
  for (int c0 = 0; c0 < 64; c0 += 8) {
    float P[8], L[8];
#pragma unroll
    for (int j = 0; j < 8; j++) { P[j] = pp[c0 + j]; L[j] = rl[(size_t)(c0 + j) * 64]; }
#pragma unroll
    for (int j = 0; j < 8; j++) {
      ri[(size_t)(c0 + j) * 64] = rin;
      rin = fmaf(P[j], rin, L[j]);
    }
  }
}

__global__ __launch_bounds__(256) void scan_apply(const u16* __restrict__ kbuf,
                                                  const float* __restrict__ sq_t,
                                                  const float* __restrict__ sv_t,
                                                  const float* __restrict__ sb_t,
                                                  const float* __restrict__ Rin,
                                                  u16* __restrict__ obuf) {
  const int wave = threadIdx.x >> 6, lane = threadIdx.x & 63;
  const int gid = blockIdx.x * 4 + wave;
  const int seq = gid >> 6, chunk = gid & 63;
  const int b = seq >> 4, h = seq & 15;
  const int t0 = chunk * 64;
  const float bet = sb_t[(size_t)seq * SEQ + t0 + lane];
  const float vs  = sv_t[(size_t)seq * SEQ + t0 + lane];
  const float qs  = sq_t[(size_t)seq * SEQ + t0 + lane];
  const u16* kp = kbuf + ((size_t)(b * SEQ + t0)) * HID + h * DH + lane;
  u16* op = obuf + ((size_t)(b * SEQ + t0)) * HID + h * DH + lane;
  float r = Rin[(size_t)gid * 64 + lane];
#pragma unroll
  for (int tt = 0; tt < 64; tt += 8) {
    u16 kr[8];
#pragma unroll
    for (int j = 0; j < 8; j++) kr[j] = kp[(size_t)(tt + j) * HID];
#pragma unroll
    for (int j = 0; j < 8; j++) {
      float bt = __shfl(bet, tt + j);
      float vt = __shfl(vs, tt + j);
      float qt = __shfl(qs, tt + j);
      r = fmaf(r, bt, bf2f(kr[j]) * vt);
      op[(size_t)(tt + j) * HID] = f2bf(qt * r);
    }
  }
}

// ---------------- LayerNorm (row per block) ----------------
__global__ __launch_bounds__(256) void ln_kernel(const u16* __restrict__ y,
                                                 const float* __restrict__ g,
                                                 const float* __restrict__ bt,
                                                 float* __restrict__ out) {
  const int row = blockIdx.x;
  const u16* yr = y + (size_t)row * HID;
  const int t = threadIdx.x;
  ushort4 u = *(const ushort4*)(yr + t * 4);
  float v0 = bf2f(u.x), v1 = bf2f(u.y), v2 = bf2f(u.z), v3 = bf2f(u.w);
  float s  = v0 + v1 + v2 + v3;
  float ss = v0 * v0 + v1 * v1 + v2 * v2 + v3 * v3;
#pragma unroll
  for (int m = 1; m < 64; m <<= 1) { s += __shfl_xor(s, m); ss += __shfl_xor(ss, m); }
  __shared__ float red[8];
  const int wave = t >> 6, lane = t & 63;
  if (lane == 0) { red[wave] = s; red[4 + wave] = ss; }
  __syncthreads();
  float st  = red[0] + red[1] + red[2] + red[3];
  float sst = red[4] + red[5] + red[6] + red[7];
  float mu  = st * (1.f / 1024.f);
  float var = sst * (1.f / 1024.f) - mu * mu;
  float inv = rsqrtf(var + 1e-5f);
  const int c = t * 4;
  float4 o;
  o.x = g[c + 0] * ((v0 - mu) * inv) + bt[c + 0];
  o.y = g[c + 1] * ((v1 - mu) * inv) + bt[c + 1];
  o.z = g[c + 2] * ((v2 - mu) * inv) + bt[c + 2];
  o.w = g[c + 3] * ((v3 - mu) * inv) + bt[c + 3];
  *(float4*)(out + (size_t)row * HID + c) = o;
}

// ---------------- launch ----------------
extern "C" void kernel_launch(void* const* d_in, const int* in_sizes, int n_in,
                              void* d_out, int out_size, void* d_ws, size_t ws_size,
                              hipStream_t stream) {
  const float* x     = (const float*)d_in[0];
  const float* Wq    = (const float*)d_in[1];
  const float* Wk    = (const float*)d_in[2];
  const float* Wv    = (const float*)d_in[3];
  const float* Wbeta = (const float*)d_in[4];
  const float* bbeta = (const float*)d_in[5];
  const float* Wo    = (const float*)d_in[6];
  const float* b_o   = (const float*)d_in[7];
  const float* ln_g  = (const float*)d_in[8];
  const float* ln_b  = (const float*)d_in[9];
  float* out = (float*)d_out;

  char* ws = (char*)d_ws;
  size_t off = 0;
  auto alloc = [&](size_t bytes) {
    char* p = ws + off; off += (bytes + 255) & ~(size_t)255; return p;
  };
  u16* xb   = (u16*)alloc((size_t)M * HID * 2);   // x bf16 (residual for EPI2)
  u16* kbuf = (u16*)alloc((size_t)M * HID * 2);   // k; reused as y after scans
  u16* obuf = (u16*)alloc((size_t)M * HID * 2);
  u16* WkT  = (u16*)alloc((size_t)HID * HID * 2);
  u16* WoT  = (u16*)alloc((size_t)HID * HID * 2);
  u16* WsT  = (u16*)alloc((size_t)64 * HID * 2);
  float* sq_t = (float*)alloc((size_t)64 * SEQ * 4);
  float* sv_t = (float*)alloc((size_t)64 * SEQ * 4);
  float* sb_t = (float*)alloc((size_t)64 * SEQ * 4);
  float* Pbuf = (float*)alloc((size_t)4096 * 4);
  float* Rloc = (float*)alloc((size_t)4096 * 64 * 4);
  float* Rin  = (float*)alloc((size_t)4096 * 64 * 4);
  u16* ybuf = kbuf;  // kbuf dead (as k) after scan_apply

  cast_x_kernel<<<8192, 256, 0, stream>>>((const float4*)x, (uint4*)xb);
  transpose_cast<<<dim3(32, 32, 2), 256, 0, stream>>>(Wk, Wo, WkT, WoT);
  build_wsum<<<256, 256, 0, stream>>>(Wq, Wv, Wbeta, WsT);

  // skinny head-stats (re-reads xb; small)
  gemm_skinny<<<M / 128, 256, 0, stream>>>(xb, WsT, bbeta, sq_t, sv_t, sb_t);

  // k = xb @ WkT^T  (256x256 phase-pipelined, 64x4 = 256 blocks = 1/CU)
  gemm256<0><<<(M / 256) * (HID / 256), 512, 0, stream>>>(
      xb, WkT, HID, kbuf, nullptr, nullptr);

  scan_chunks<<<1024, 256, 0, stream>>>(kbuf, sv_t, sb_t, Pbuf, Rloc);
  scan_prefix<<<64, 64, 0, stream>>>(Pbuf, Rloc, Rin);
  scan_apply<<<1024, 256, 0, stream>>>(kbuf, sq_t, sv_t, sb_t, Rin, obuf);

  // y = bf16(xb + obuf @ WoT^T + b_o), written over kbuf (k dead)
  gemm256<2><<<(M / 256) * (HID / 256), 512, 0, stream>>>(
      obuf, WoT, HID, ybuf, xb, b_o);

  ln_kernel<<<M, 256, 0, stream>>>(ybuf, ln_g, ln_b, out);
}

// Round 8
// 158.367 us; speedup vs baseline: 1.3234x; 1.0301x over previous
//
#include <hip/hip_runtime.h>
#include <hip/hip_bf16.h>

typedef unsigned short u16;
typedef unsigned int   u32;
typedef u32 __attribute__((address_space(1))) gas_u32;
typedef u32 __attribute__((address_space(3))) las_u32;
typedef __bf16 bf16x8 __attribute__((ext_vector_type(8)));
typedef float  f32x4  __attribute__((ext_vector_type(4)));

constexpr int BATCH = 4, SEQ = 4096, HID = 1024, NH = 16, DH = 64;
constexpr int M  = BATCH * SEQ;   // 16384 rows
constexpr int KD = HID;           // 1024 (K of all GEMMs)

__device__ __forceinline__ u16 f2bf(float f) {
  __hip_bfloat16 h = __float2bfloat16(f);
  u16 u; __builtin_memcpy(&u, &h, 2); return u;
}
__device__ __forceinline__ float bf2f(u16 u) {
  u32 x = ((u32)u) << 16; float f; __builtin_memcpy(&f, &x, 4); return f;
}

// ---------------- prep kernels ----------------

__global__ __launch_bounds__(256) void transpose_cast(const float* __restrict__ Wk,
                                                      const float* __restrict__ Wo,
                                                      u16* __restrict__ WkT,
                                                      u16* __restrict__ WoT) {
  __shared__ float tile[32][33];
  const float* src = blockIdx.z ? Wo : Wk;
  u16* dst = blockIdx.z ? WoT : WkT;
  int bx = blockIdx.x * 32, by = blockIdx.y * 32;
  int tx = threadIdx.x & 31, ty = threadIdx.x >> 5;
#pragma unroll
  for (int i = 0; i < 4; i++)
    tile[ty + i * 8][tx] = src[(size_t)(by + ty + i * 8) * HID + bx + tx];
  __syncthreads();
#pragma unroll
  for (int i = 0; i < 4; i++)
    dst[(size_t)(bx + ty + i * 8) * HID + by + tx] = f2bf(tile[tx][ty + i * 8]);
}

// WsT (64 x 1024 bf16): rows 0..15 colsum(Wq)/head, 16..31 colsum(Wv), 32..47 Wbeta, 48..63 zero
__global__ __launch_bounds__(256) void build_wsum(const float* __restrict__ Wq,
                                                  const float* __restrict__ Wv,
                                                  const float* __restrict__ Wbeta,
                                                  u16* __restrict__ WsT) {
  int tid = blockIdx.x * 256 + threadIdx.x;   // 65536
  int c = tid >> 10, kk = tid & 1023;
  float s = 0.f;
  if (c < 16)      { for (int d = 0; d < DH; d++) s += Wq[(size_t)kk * HID + c * DH + d]; }
  else if (c < 32) { for (int d = 0; d < DH; d++) s += Wv[(size_t)kk * HID + (c - 16) * DH + d]; }
  else if (c < 48) { s = Wbeta[(size_t)kk * NH + (c - 32)]; }
  WsT[(size_t)c * HID + kk] = f2bf(s);
}

// ======== fused cast + head-stat GEMM: reads fp32 x, emits xb (bf16) + stats ========
// BM=64, BN=64, BK=64, 256 threads (4 waves, 16 rows each). A is reg-staged
// (fp32 -> bf16 cvt) into LDS and simultaneously stored to xb (same bits as
// the old cast_x, so downstream results are bit-identical). B (WsT) staged
// via global_load_lds. Stats epilogue: transposed [seq][t] fp32, sigmoid beta.
__global__ __launch_bounds__(256) void skinny_fused(
    const float* __restrict__ x, const u16* __restrict__ Bt,
    const float* __restrict__ bias, float* __restrict__ sq,
    float* __restrict__ sv, float* __restrict__ sb, u16* __restrict__ xb) {
  constexpr int BM = 64, BK = 64;
  __shared__ u16 As[BM * BK];
  __shared__ u16 Bs[64 * BK];
  const int tid = threadIdx.x, wave = tid >> 6, lane = tid & 63;
  const int bm = blockIdx.x;
  const int r16 = lane & 15, hi = lane >> 4;
  const int rsub = lane >> 3, csub = (lane & 7) * 8;
  f32x4 acc[4] = {};
  const float* Ab = x + (size_t)bm * BM * KD;
  u16* xbb = xb + (size_t)bm * BM * KD;

  for (int kt = 0; kt < KD; kt += BK) {
    // B tile: async global->LDS
#pragma unroll
    for (int i = 0; i < 2; i++) {
      int slot = wave * 2 + i;
      const u16* g = Bt + (size_t)(slot * 8 + rsub) * KD + kt + csub;
      __builtin_amdgcn_global_load_lds((const gas_u32*)g, (las_u32*)(Bs + slot * 512), 16, 0, 0);
    }
    // A tile: reg-staged fp32 -> bf16 (also written out to xb)
#pragma unroll
    for (int p = 0; p < 2; p++) {
      const int row = p * 32 + (tid >> 3);
      const int c8 = (tid & 7) * 8;
      const float4 u0 = *(const float4*)(Ab + (size_t)row * KD + kt + c8);
      const float4 u1 = *(const float4*)(Ab + (size_t)row * KD + kt + c8 + 4);
      uint4 w;
      w.x = (u32)f2bf(u0.x) | ((u32)f2bf(u0.y) << 16);
      w.y = (u32)f2bf(u0.z) | ((u32)f2bf(u0.w) << 16);
      w.z = (u32)f2bf(u1.x) | ((u32)f2bf(u1.y) << 16);
      w.w = (u32)f2bf(u1.z) | ((u32)f2bf(u1.w) << 16);
      *(uint4*)(As + row * BK + c8) = w;
      *(uint4*)(xbb + (size_t)row * KD + kt + c8) = w;
    }
    __syncthreads();   // drains vmcnt (B DMA) + lgkmcnt (A ds_writes)
#pragma unroll
    for (int kk = 0; kk < 2; kk++) {
      bf16x8 af = *(const bf16x8*)(As + (wave * 16 + r16) * BK + kk * 32 + hi * 8);
#pragma unroll
      for (int fn = 0; fn < 4; fn++) {
        bf16x8 bfr = *(const bf16x8*)(Bs + (fn * 16 + r16) * BK + kk * 32 + hi * 8);
        acc[fn] = __builtin_amdgcn_mfma_f32_16x16x32_bf16(af, bfr, acc[fn], 0, 0, 0);
      }
    }
    __syncthreads();
  }

#pragma unroll
  for (int fn = 0; fn < 4; fn++) {
    const int col = fn * 16 + r16;
#pragma unroll
    for (int j = 0; j < 4; j++) {
      const int row = bm * BM + wave * 16 + hi * 4 + j;
      const int b = row >> 12, t = row & 4095;
      float v = acc[fn][j];
      if (col < 16)      sq[((size_t)(b * 16 + col)) * SEQ + t] = v;
      else if (col < 32) sv[((size_t)(b * 16 + col - 16)) * SEQ + t] = v;
      else if (col < 48) {
        float z = v + bias[col - 32];
        sb[((size_t)(b * 16 + col - 32)) * SEQ + t] = 1.f / (1.f + __expf(-z));
      }
    }
  }
}

// ============ 256x256 8-wave phase-pipelined MFMA GEMM (T2+T3+T4+T5) ============
// C(MxN) = A(MxK) * Bt(NxK)^T, K=1024, BK=64, 512 threads (8 waves, 2M x 4N).
// LDS: 2 dbuf x (A 256x64 + B 256x64) bf16 = 128 KiB -> 1 block/CU.
// Register-blocked phases (m-half x kk-slice): B-frags read once per kk into
// bF[4][2]; A-frags once each -> 24 ds_read_b128 per K-tile (8/8/4/4).
//
// Sync (verified R6/R7): vmcnt is PER-WAVE while tiles are filled by ALL
// waves -> every counted wait precedes an s_barrier BEFORE dependent ds_reads.
// end-ph1 vmcnt(4) completes current A1,A3; end-ph3 vmcnt(2) completes next
// A0,A2,B0-3 (leaves nA1,nA3). Never 0 in steady loop.
//
// R8: last K-tile peeled (no staging; dead re-stage of tile 0 cost 16 MB of
// cold FETCH across the grid). Peeled ph1 drains with vmcnt(0) (queue is
// exactly [A1,A3] there), preserving the wait->barrier->read invariant.

__device__ __forceinline__ void stage_quarter(const u16* __restrict__ Gk,
                                              int q, u16* lds_tile, int tid, int wave) {
  const int row = q * 64 + (tid >> 3);          // 64 rows per quarter
  const int s = tid & 7;                        // 16B col-group
  const u16* g = Gk + (size_t)row * KD + (size_t)((s ^ (row & 7)) << 3);
  u16* l = lds_tile + q * 4096 + wave * 512;    // wave-uniform LDS base, lanes +16B
  __builtin_amdgcn_global_load_lds((const gas_u32*)g, (las_u32*)l, 16, 0, 0);
}

__device__ __forceinline__ const bf16x8* lds_frag(const u16* lds_tile, int row, int cg) {
  return (const bf16x8*)(lds_tile + ((size_t)row << 6) + (size_t)((cg ^ (row & 7)) << 3));
}

// EPI 0: C = bf16(acc). EPI 2: C = bf16(xres + acc + bias).
template <int EPI>
__global__ __launch_bounds__(512) void gemm256(
    const u16* __restrict__ A, const u16* __restrict__ Bt, int N,
    u16* __restrict__ Cb, const u16* __restrict__ xres, const float* __restrict__ bias) {
  constexpr int BK = 64, NT = KD / BK;  // 16 K-tiles
  __shared__ u16 lds[2][2][16384];      // [buf][A=0/B=1][256*64]
  const int tid = threadIdx.x, wave = tid >> 6, lane = tid & 63;
  const int wm = wave >> 2, wn = wave & 3;
  const int r16 = lane & 15, hi = lane >> 4;
  const int nbn = N >> 8;
  const int bm = (int)blockIdx.x / nbn, bn = (int)blockIdx.x % nbn;
  const u16* Abase = A + (size_t)bm * 256 * KD;
  const u16* Bbase = Bt + (size_t)bn * 256 * KD;

  f32x4 acc[8][4] = {};

  // prologue: stage tile 0 into buf0. Oldest-6 = A0,A2,B0..B3 (needed at ph0);
  // A1,A3 stay in flight, completed by kt0-ph1's vmcnt(4).
  {
    u16* la = &lds[0][0][0]; u16* lb = &lds[0][1][0];
    stage_quarter(Abase, 0, la, tid, wave);
    stage_quarter(Abase, 2, la, tid, wave);
    stage_quarter(Bbase, 0, lb, tid, wave);
    stage_quarter(Bbase, 1, lb, tid, wave);
    stage_quarter(Bbase, 2, lb, tid, wave);
    stage_quarter(Bbase, 3, lb, tid, wave);
    stage_quarter(Abase, 1, la, tid, wave);
    stage_quarter(Abase, 3, la, tid, wave);
  }
  asm volatile("s_waitcnt vmcnt(2)" ::: "memory");
  __builtin_amdgcn_s_barrier();

  for (int kt = 0; kt < NT - 1; ++kt) {
    const int cur = kt & 1;
    const u16* la = &lds[cur][0][0];
    const u16* lb = &lds[cur][1][0];
    u16* na = &lds[cur ^ 1][0][0];
    u16* nb = &lds[cur ^ 1][1][0];
    const u16* An = Abase + (kt + 1) * BK;
    const u16* Bn = Bbase + (kt + 1) * BK;

    bf16x8 bF[4][2];   // wave's n-stripe B fragments, persistent across phases
#pragma unroll
    for (int ph = 0; ph < 4; ++ph) {
      const int mh = ph >> 1;     // m-half
      const int kk = ph & 1;      // K-slice of 32
      if (ph == 0)      { stage_quarter(An, 0, na, tid, wave); stage_quarter(An, 2, na, tid, wave); }
      else if (ph == 1) { stage_quarter(Bn, 0, nb, tid, wave); stage_quarter(Bn, 1, nb, tid, wave); }
      else if (ph == 2) { stage_quarter(Bn, 2, nb, tid, wave); stage_quarter(Bn, 3, nb, tid, wave); }
      else              { stage_quarter(An, 1, na, tid, wave); stage_quarter(An, 3, na, tid, wave); }
      bf16x8 aF[4];
#pragma unroll
      for (int f = 0; f < 4; ++f)
        aF[f] = *lds_frag(la, wm * 128 + mh * 64 + f * 16 + r16, kk * 4 + hi);
      if (ph < 2) {
#pragma unroll
        for (int g = 0; g < 4; ++g)
          bF[g][kk] = *lds_frag(lb, wn * 64 + g * 16 + r16, kk * 4 + hi);
      }
      __builtin_amdgcn_s_barrier();
      asm volatile("s_waitcnt lgkmcnt(0)" ::: "memory");
      __builtin_amdgcn_sched_barrier(0);          // rule #18
      __builtin_amdgcn_s_setprio(1);
#pragma unroll
      for (int f = 0; f < 4; ++f)
#pragma unroll
        for (int g = 0; g < 4; ++g)
          acc[mh * 4 + f][g] = __builtin_amdgcn_mfma_f32_16x16x32_bf16(
              aF[f], bF[g][kk], acc[mh * 4 + f][g], 0, 0, 0);
      __builtin_amdgcn_s_setprio(0);
      if (ph == 1) { asm volatile("s_waitcnt vmcnt(4)" ::: "memory"); }  // completes cA1,cA3
      if (ph == 3) { asm volatile("s_waitcnt vmcnt(2)" ::: "memory"); }  // completes nA0,nA2,nB0-3
      __builtin_amdgcn_s_barrier();
    }
  }

  // last K-tile (peeled): no staging. Queue entering: [A1,A3] of this tile.
  {
    const u16* la = &lds[(NT - 1) & 1][0][0];
    const u16* lb = &lds[(NT - 1) & 1][1][0];
    bf16x8 bF[4][2];
#pragma unroll
    for (int ph = 0; ph < 4; ++ph) {
      const int mh = ph >> 1, kk = ph & 1;
      bf16x8 aF[4];
#pragma unroll
      for (int f = 0; f < 4; ++f)
        aF[f] = *lds_frag(la, wm * 128 + mh * 64 + f * 16 + r16, kk * 4 + hi);
      if (ph < 2) {
#pragma unroll
        for (int g = 0; g < 4; ++g)
          bF[g][kk] = *lds_frag(lb, wn * 64 + g * 16 + r16, kk * 4 + hi);
      }
      __builtin_amdgcn_s_barrier();
      asm volatile("s_waitcnt lgkmcnt(0)" ::: "memory");
      __builtin_amdgcn_sched_barrier(0);
      __builtin_amdgcn_s_setprio(1);
#pragma unroll
      for (int f = 0; f < 4; ++f)
#pragma unroll
        for (int g = 0; g < 4; ++g)
          acc[mh * 4 + f][g] = __builtin_amdgcn_mfma_f32_16x16x32_bf16(
              aF[f], bF[g][kk], acc[mh * 4 + f][g], 0, 0, 0);
      __builtin_amdgcn_s_setprio(0);
      if (ph == 1) { asm volatile("s_waitcnt vmcnt(0)" ::: "memory"); }  // drain A1,A3
      __builtin_amdgcn_s_barrier();
    }
  }

  // epilogue
#pragma unroll
  for (int fm = 0; fm < 8; ++fm) {
#pragma unroll
    for (int fn = 0; fn < 4; ++fn) {
      const int col = bn * 256 + wn * 64 + fn * 16 + r16;
#pragma unroll
      for (int j = 0; j < 4; ++j) {
        const int row = bm * 256 + wm * 128 + fm * 16 + hi * 4 + j;
        float v = acc[fm][fn][j];
        if constexpr (EPI == 2) v += bf2f(xres[(size_t)row * N + col]) + bias[col];
        Cb[(size_t)row * N + col] = f2bf(v);
      }
    }
  }
}

// ---------------- chunked scan: r_t = b_t*r_{t-1} + k_t*vsum_t ----------------

__global__ __launch_bounds__(256) void scan_chunks(const u16* __restrict__ kbuf,
                                                   const float* __restrict__ sv_t,
                                                   const float* __restrict__ sb_t,
                                                   float* __restrict__ Pbuf,
                                                   float* __restrict__ Rloc) {
  const int wave = threadIdx.x >> 6, lane = threadIdx.x & 63;
  const int gid = blockIdx.x * 4 + wave;
  const int seq = gid >> 6, chunk = gid & 63;
  const int b = seq >> 4, h = seq & 15;
  const int t0 = chunk * 64;
  const float bet = sb_t[(size_t)seq * SEQ + t0 + lane];
  const float vs  = sv_t[(size_t)seq * SEQ + t0 + lane];
  const u16* kp = kbuf + ((size_t)(b * SEQ + t0)) * HID + h * DH + lane;
  float r = 0.f, P = 1.f;
#pragma unroll
  for (int tt = 0; tt < 64; tt += 8) {
    u16 kr[8];
#pragma unroll
    for (int j = 0; j < 8; j++) kr[j] = kp[(size_t)(tt + j) * HID];
#pragma unroll
    for (int j = 0; j < 8; j++) {
      float bt = __shfl(bet, tt + j);
      float vt = __shfl(vs, tt + j);
      r = fmaf(r, bt, bf2f(kr[j]) * vt);
      P *= bt;
    }
  }
  Rloc[(size_t)gid * 64 + lane] = r;
  if (lane == 0) Pbuf[gid] = P;
}

__global__ __launch_bounds__(64) void scan_prefix(const float* __restrict__ Pbuf,
                                                  const float* __restrict__ Rloc,
                                                  float* __restrict__ Rin) {
  const int seq = blockIdx.x, lane = threadIdx.x;
  const float* pp = Pbuf + seq * 64;
  const float* rl = Rloc + (size_t)seq * 64 * 64 + lane;
  float* ri = Rin + (size_t)seq * 64 * 64 + lane;
  float rin = 0.f;
#pragma unroll
  for (int c0 = 0; c0 < 64; c0 += 8) {
    float P[8], L[8];
#pragma unroll
    for (int j = 0; j < 8; j++) { P[j] = pp[c0 + j]; L[j] = rl[(size_t)(c0 + j) * 64]; }
#pragma unroll
    for (int j = 0; j < 8; j++) {
      ri[(size_t)(c0 + j) * 64] = rin;
      rin = fmaf(P[j], rin, L[j]);
    }
  }
}

__global__ __launch_bounds__(256) void scan_apply(const u16* __restrict__ kbuf,
                                                  const float* __restrict__ sq_t,
                                                  const float* __restrict__ sv_t,
                                                  const float* __restrict__ sb_t,
                                                  const float* __restrict__ Rin,
                                                  u16* __restrict__ obuf) {
  const int wave = threadIdx.x >> 6, lane = threadIdx.x & 63;
  const int gid = blockIdx.x * 4 + wave;
  const int seq = gid >> 6, chunk = gid & 63;
  const int b = seq >> 4, h = seq & 15;
  const int t0 = chunk * 64;
  const float bet = sb_t[(size_t)seq * SEQ + t0 + lane];
  const float vs  = sv_t[(size_t)seq * SEQ + t0 + lane];
  const float qs  = sq_t[(size_t)seq * SEQ + t0 + lane];
  const u16* kp = kbuf + ((size_t)(b * SEQ + t0)) * HID + h * DH + lane;
  u16* op = obuf + ((size_t)(b * SEQ + t0)) * HID + h * DH + lane;
  float r = Rin[(size_t)gid * 64 + lane];
#pragma unroll
  for (int tt = 0; tt < 64; tt += 8) {
    u16 kr[8];
#pragma unroll
    for (int j = 0; j < 8; j++) kr[j] = kp[(size_t)(tt + j) * HID];
#pragma unroll
    for (int j = 0; j < 8; j++) {
      float bt = __shfl(bet, tt + j);
      float vt = __shfl(vs, tt + j);
      float qt = __shfl(qs, tt + j);
      r = fmaf(r, bt, bf2f(kr[j]) * vt);
      op[(size_t)(tt + j) * HID] = f2bf(qt * r);
    }
  }
}

// ---------------- LayerNorm (row per block) ----------------
__global__ __launch_bounds__(256) void ln_kernel(const u16* __restrict__ y,
                                                 const float* __restrict__ g,
                                                 const float* __restrict__ bt,
                                                 float* __restrict__ out) {
  const int row = blockIdx.x;
  const u16* yr = y + (size_t)row * HID;
  const int t = threadIdx.x;
  ushort4 u = *(const ushort4*)(yr + t * 4);
  float v0 = bf2f(u.x), v1 = bf2f(u.y), v2 = bf2f(u.z), v3 = bf2f(u.w);
  float s  = v0 + v1 + v2 + v3;
  float ss = v0 * v0 + v1 * v1 + v2 * v2 + v3 * v3;
#pragma unroll
  for (int m = 1; m < 64; m <<= 1) { s += __shfl_xor(s, m); ss += __shfl_xor(ss, m); }
  __shared__ float red[8];
  const int wave = t >> 6, lane = t & 63;
  if (lane == 0) { red[wave] = s; red[4 + wave] = ss; }
  __syncthreads();
  float st  = red[0] + red[1] + red[2] + red[3];
  float sst = red[4] + red[5] + red[6] + red[7];
  float mu  = st * (1.f / 1024.f);
  float var = sst * (1.f / 1024.f) - mu * mu;
  float inv = rsqrtf(var + 1e-5f);
  const int c = t * 4;
  float4 o;
  o.x = g[c + 0] * ((v0 - mu) * inv) + bt[c + 0];
  o.y = g[c + 1] * ((v1 - mu) * inv) + bt[c + 1];
  o.z = g[c + 2] * ((v2 - mu) * inv) + bt[c + 2];
  o.w = g[c + 3] * ((v3 - mu) * inv) + bt[c + 3];
  *(float4*)(out + (size_t)row * HID + c) = o;
}

// ---------------- launch ----------------
extern "C" void kernel_launch(void* const* d_in, const int* in_sizes, int n_in,
                              void* d_out, int out_size, void* d_ws, size_t ws_size,
                              hipStream_t stream) {
  const float* x     = (const float*)d_in[0];
  const float* Wq    = (const float*)d_in[1];
  const float* Wk    = (const float*)d_in[2];
  const float* Wv    = (const float*)d_in[3];
  const float* Wbeta = (const float*)d_in[4];
  const float* bbeta = (const float*)d_in[5];
  const float* Wo    = (const float*)d_in[6];
  const float* b_o   = (const float*)d_in[7];
  const float* ln_g  = (const float*)d_in[8];
  const float* ln_b  = (const float*)d_in[9];
  float* out = (float*)d_out;

  char* ws = (char*)d_ws;
  size_t off = 0;
  auto alloc = [&](size_t bytes) {
    char* p = ws + off; off += (bytes + 255) & ~(size_t)255; return p;
  };
  u16* xb   = (u16*)alloc((size_t)M * HID * 2);   // x bf16 (residual for EPI2)
  u16* kbuf = (u16*)alloc((size_t)M * HID * 2);   // k; reused as y after scans
  u16* obuf = (u16*)alloc((size_t)M * HID * 2);
  u16* WkT  = (u16*)alloc((size_t)HID * HID * 2);
  u16* WoT  = (u16*)alloc((size_t)HID * HID * 2);
  u16* WsT  = (u16*)alloc((size_t)64 * HID * 2);
  float* sq_t = (float*)alloc((size_t)64 * SEQ * 4);
  float* sv_t = (float*)alloc((size_t)64 * SEQ * 4);
  float* sb_t = (float*)alloc((size_t)64 * SEQ * 4);
  float* Pbuf = (float*)alloc((size_t)4096 * 4);
  float* Rloc = (float*)alloc((size_t)4096 * 64 * 4);
  float* Rin  = (float*)alloc((size_t)4096 * 64 * 4);
  u16* ybuf = kbuf;  // kbuf dead (as k) after scan_apply

  transpose_cast<<<dim3(32, 32, 2), 256, 0, stream>>>(Wk, Wo, WkT, WoT);
  build_wsum<<<256, 256, 0, stream>>>(Wq, Wv, Wbeta, WsT);

  // fused cast + head-stats: produces xb AND sq/sv/sb in one pass over x
  skinny_fused<<<M / 64, 256, 0, stream>>>(x, WsT, bbeta, sq_t, sv_t, sb_t, xb);

  // k = xb @ WkT^T  (256x256 phase-pipelined, 64x4 = 256 blocks = 1/CU)
  gemm256<0><<<(M / 256) * (HID / 256), 512, 0, stream>>>(
      xb, WkT, HID, kbuf, nullptr, nullptr);

  scan_chunks<<<1024, 256, 0, stream>>>(kbuf, sv_t, sb_t, Pbuf, Rloc);
  scan_prefix<<<64, 64, 0, stream>>>(Pbuf, Rloc, Rin);
  scan_apply<<<1024, 256, 0, stream>>>(kbuf, sq_t, sv_t, sb_t, Rin, obuf);

  // y = bf16(xb + obuf @ WoT^T + b_o), written over kbuf (k dead)
  gemm256<2><<<(M / 256) * (HID / 256), 512, 0, stream>>>(
      obuf, WoT, HID, ybuf, xb, b_o);

  ln_kernel<<<M, 256, 0, stream>>>(ybuf, ln_g, ln_b, out);
}